// Round 1
// baseline (477.427 us; speedup 1.0000x reference)
//
#include <hip/hip_runtime.h>
#include <hip/hip_cooperative_groups.h>
#include <math.h>

namespace cg = cooperative_groups;

#define NB 64
#define LIN 4001
#define LC 998
#define ND 1000
#define EPSBN 1e-5f

#define CKL 100          // K-chunk for QKV GEMM -> 10 chunks * 3 * 16 = 480 units
#define NCHL 10
#define CKO 32           // K-chunk for out GEMM -> 32 chunks * 16 = 512 units
#define NCHO 32
#define GRID_BLOCKS 512

// ws float offsets
#define OFF_CONVT 0u          // 3*998*64     = 191616
#define OFF_PP    191616u     // 10*3*16*4096 = 1966080
#define OFF_Q     2157696u    // 64*1000      = 64000
#define OFF_KV    2221696u    // 64*2048      = 131072
#define OFF_CF    2352768u    // 1000*64      = 64000
#define OFF_OP    2416768u    // 32*16*4096   = 2097152
// end = 4513920 floats = 18.1 MB

struct KParams {
    const float *x, *g, *be, *mu, *va;
    const float *cwq, *cbq, *lwq, *lbq;
    const float *cwk, *cbk, *lwk, *lbk;
    const float *cwv, *cbv, *lwv, *lbv;
    const float *ipw, *ipb, *opw, *opb, *W, *outb;
    float *convT, *Pp, *q, *kv, *cfT, *Op, *out;
};

// ---------------- shared GEMM microtile body (64b x 64d x CKT) --------------
template <int CKT>
__device__ __forceinline__ void gemm_tile(
    const float* __restrict__ Asrc,   // [jc][64] chunk, b-contiguous
    const float* __restrict__ Brow,   // weight base, row stride ldB
    int ldB, int dgb, int j0, int jc,
    float* __restrict__ Pt,           // output tile [64 b][64 d]
    float* lds)
{
    constexpr int LDW = CKT + 1;
    constexpr int F2R = CKT / 2;
    float* ldsC = lds;                // [CKT][64]
    float* ldsW = lds + CKT * 64;     // [64][LDW]
    int tid  = threadIdx.x;
    int lane = tid & 63;
    int w    = tid >> 6;
    int b0   = (lane & 7) << 3;
    int d0   = (lane >> 3) << 3;

    {   // stage A chunk via float4 (fully coalesced)
        const float4* src = (const float4*)Asrc;
        float4* dst = (float4*)ldsC;
        int n = jc * 16;
        for (int t = tid; t < n; t += 256) dst[t] = src[t];
    }
    // stage B tile via float2 (row starts & j0 are even)
    for (int idx = tid; idx < 64 * F2R; idx += 256) {
        int dd = idx / F2R, j2 = idx % F2R;
        int dg = dgb + dd;
        float2 v = make_float2(0.f, 0.f);
        if (dg < ND && 2 * j2 < jc)
            v = *(const float2*)(Brow + (size_t)dg * ldB + j0 + 2 * j2);
        ldsW[dd * LDW + 2 * j2]     = v.x;
        ldsW[dd * LDW + 2 * j2 + 1] = v.y;
    }
    __syncthreads();

    float acc[8][8];
#pragma unroll
    for (int i = 0; i < 8; ++i)
#pragma unroll
        for (int jx = 0; jx < 8; ++jx) acc[i][jx] = 0.f;

    int js = (jc * w) >> 2;
    int je = (jc * (w + 1)) >> 2;
    for (int jj = js; jj < je; ++jj) {
        float4 c0 = *(const float4*)(ldsC + jj * 64 + b0);
        float4 c1 = *(const float4*)(ldsC + jj * 64 + b0 + 4);
        float cv[8] = {c0.x, c0.y, c0.z, c0.w, c1.x, c1.y, c1.z, c1.w};
        float wv[8];
#pragma unroll
        for (int r = 0; r < 8; ++r) wv[r] = ldsW[(d0 + r) * LDW + jj];
#pragma unroll
        for (int i = 0; i < 8; ++i)
#pragma unroll
            for (int jx = 0; jx < 8; ++jx)
                acc[i][jx] = fmaf(cv[i], wv[jx], acc[i][jx]);
    }
    __syncthreads();   // done with staged data; reuse LDS for reduce

    // two passes (f4 halves of each lane's d-range); per-wave buf [64][36]
    for (int p = 0; p < 2; ++p) {
        float* red = lds + w * 2304;
#pragma unroll
        for (int i = 0; i < 8; ++i)
            *(float4*)(red + (b0 + i) * 36 + (d0 >> 1)) =
                make_float4(acc[i][4*p], acc[i][4*p+1], acc[i][4*p+2], acc[i][4*p+3]);
        __syncthreads();
        for (int t = tid; t < 512; t += 256) {
            int bb = t >> 3, gg = t & 7;
            int o = bb * 36 + 4 * gg;
            float4 a0 = *(const float4*)(lds + o);
            float4 a1 = *(const float4*)(lds + 2304 + o);
            float4 a2 = *(const float4*)(lds + 4608 + o);
            float4 a3 = *(const float4*)(lds + 6912 + o);
            float4 s;
            s.x = a0.x + a1.x + a2.x + a3.x;
            s.y = a0.y + a1.y + a2.y + a3.y;
            s.z = a0.z + a1.z + a2.z + a3.z;
            s.w = a0.w + a1.w + a2.w + a3.w;
            *(float4*)(Pt + bb * 64 + 8 * gg + 4 * p) = s;
        }
        __syncthreads();
    }
}

// ---------------- phase bodies ---------------------------------------------
__device__ __forceinline__ void ph_conv(const KParams& p, int jt, int b, int tid)
{
    int j = jt * 256 + tid;
    if (j < LC) {
        const float* xb = p.x + (size_t)b * LIN + 4 * j;
        float aq = 0.f, ak = 0.f, av = 0.f;
#pragma unroll
        for (int t = 0; t < 10; ++t) {
            int i = 4 * j + t;
            float s  = p.g[i] * rsqrtf(p.va[i] + EPSBN);
            float xn = (xb[t] - p.mu[i]) * s + p.be[i];
            aq = fmaf(xn, p.cwq[t], aq);
            ak = fmaf(xn, p.cwk[t], ak);
            av = fmaf(xn, p.cwv[t], av);
        }
        p.convT[((size_t)0 * LC + j) * 64 + b] = aq + p.cbq[0];
        p.convT[((size_t)1 * LC + j) * 64 + b] = ak + p.cbk[0];
        p.convT[((size_t)2 * LC + j) * 64 + b] = av + p.cbv[0];
    }
}

__device__ __forceinline__ void ph_lin(const KParams& p, int chunk, int which,
                                       int dgx, float* smem)
{
    int j0 = chunk * CKL;
    int jc = (LC - j0 < CKL) ? (LC - j0) : CKL;
    const float* lw = (which == 0) ? p.lwq : ((which == 1) ? p.lwk : p.lwv);
    const float* Asrc = p.convT + ((size_t)which * LC + j0) * 64;
    float* Pt = p.Pp + (((size_t)chunk * 3 + which) * 16 + dgx) * 4096;
    gemm_tile<CKL>(Asrc, lw, LC, dgx * 64, j0, jc, Pt, smem);
}

__device__ __forceinline__ void ph_act(const KParams& p, int it, int b, int tid)
{
    int i = it * 256 + tid;
    if (i < ND) {
        int ig = i >> 6, il = i & 63;
        float s0 = 0.f, s1 = 0.f, s2 = 0.f;
        for (int c = 0; c < NCHL; ++c) {
            size_t base = (((size_t)c * 3) * 16 + ig) * 4096 + (il | (b << 6));
            s0 += p.Pp[base];
            s1 += p.Pp[base + 16 * 4096];
            s2 += p.Pp[base + 32 * 4096];
        }
        float yq = fmaxf(s0 + p.lbq[i], 0.f) * p.ipw[0] + p.ipb[0];
        float yk = fmaxf(s1 + p.lbk[i], 0.f) * p.ipw[1] + p.ipb[1];
        float yv = fmaxf(s2 + p.lbv[i], 0.f) * p.ipw[2] + p.ipb[2];
        p.q[(size_t)b * ND + i] = yq;
        p.kv[(size_t)b * 2048 + 2 * i]     = yk;
        p.kv[(size_t)b * 2048 + 2 * i + 1] = yv;
    }
}

__device__ __forceinline__ void ph_attn(const KParams& p, int it, int b,
                                        int tid, float* smem)
{
    float* ldsKV = smem;          // 2048
    float* sden  = smem + 2048;   // 256
    float* snum  = smem + 2304;   // 256
    float* rmax  = smem + 2560;   // 4
    float* rmin  = smem + 2564;   // 4
    int w  = tid >> 6;
    int ii = tid & 63;
    int i  = it * 64 + ii;

    {   // stage kv[b] (8 KB)
        const float4* src = (const float4*)(p.kv + (size_t)b * 2048);
        float4* dst = (float4*)ldsKV;
        for (int t = tid; t < 512; t += 256) dst[t] = src[t];
    }
    __syncthreads();

    const float2* kv2 = (const float2*)ldsKV;
    float km = -INFINITY, kn = INFINITY;
    for (int idx = tid; idx < ND; idx += 256) {
        float2 f = kv2[idx];
        km = fmaxf(km, f.x);
        kn = fminf(kn, f.x);
    }
#pragma unroll
    for (int off = 1; off < 64; off <<= 1) {
        km = fmaxf(km, __shfl_xor(km, off));
        kn = fminf(kn, __shfl_xor(kn, off));
    }
    if (ii == 0) { rmax[w] = km; rmin[w] = kn; }
    __syncthreads();
    km = fmaxf(fmaxf(rmax[0], rmax[1]), fmaxf(rmax[2], rmax[3]));
    kn = fminf(fminf(rmin[0], rmin[1]), fminf(rmin[2], rmin[3]));

    float qi = (i < ND) ? p.q[(size_t)b * ND + i] : 0.f;
    float m  = (qi >= 0.f) ? qi * km : qi * kn;

    int jb = w * 250;
    float den = 0.f, num = 0.f;
#pragma unroll 2
    for (int jl = 0; jl < 250; ++jl) {
        float2 f = kv2[jb + jl];
        float e  = __expf(fmaf(qi, f.x, -m));
        den += e;
        num = fmaf(e, f.y, num);
    }
    sden[tid] = den;
    snum[tid] = num;
    __syncthreads();
    if (w == 0 && i < ND) {
        float dt = sden[ii] + sden[64 + ii] + sden[128 + ii] + sden[192 + ii];
        float nt = snum[ii] + snum[64 + ii] + snum[128 + ii] + snum[192 + ii];
        p.cfT[(size_t)i * 64 + b] = (nt / dt) * p.opw[0] + p.opb[0];
    }
    __syncthreads();   // protect LDS before next unit re-stages
}

__device__ __forceinline__ void ph_out(const KParams& p, int chunk, int dgx,
                                       float* smem)
{
    int j0 = chunk * CKO;
    int jc = (ND - j0 < CKO) ? (ND - j0) : CKO;
    const float* Asrc = p.cfT + (size_t)j0 * 64;
    float* Pt = p.Op + ((size_t)chunk * 16 + dgx) * 4096;
    gemm_tile<CKO>(Asrc, p.W, ND, dgx * 64, j0, jc, Pt, smem);
}

__device__ __forceinline__ void ph_fin(const KParams& p, int it, int b, int tid)
{
    int e = it * 256 + tid;
    if (e < ND) {
        float s = p.outb[e];
        size_t cell = ((size_t)(e >> 6)) * 4096 + (b << 6) + (e & 63);
        for (int c = 0; c < NCHO; ++c)
            s += p.Op[(size_t)c * 16 * 4096 + cell];
        p.out[(size_t)b * ND + e] = s;
    }
}

// ---------------- fused cooperative kernel ----------------------------------
__global__ __launch_bounds__(256, 3) void k_all(KParams p)
{
    __shared__ float smem[12864];   // 51456 B: max(P2 staging 12864, reduce 9216)
    cg::grid_group grid = cg::this_grid();
    const int tid = threadIdx.x;
    const int bid = blockIdx.x;

    // P1: BN + strided conv (256 units)
    if (bid < 256) ph_conv(p, bid & 3, bid >> 2, tid);
    grid.sync();

    // P2: QKV GEMM partials (480 units, one per block)
    if (bid < 480) {
        int chunk = bid / 48, rem = bid % 48;
        ph_lin(p, chunk, rem >> 4, rem & 15, smem);
    }
    grid.sync();

    // P3: chunk-reduce + bias + ReLU + in_proj (256 units)
    if (bid < 256) ph_act(p, bid & 3, bid >> 2, tid);
    grid.sync();

    // P4: attention (1024 units, 2 per block)
    for (int u = bid; u < 1024; u += GRID_BLOCKS)
        ph_attn(p, u & 15, u >> 4, tid, smem);
    grid.sync();

    // P5: out GEMM partials (512 units, exactly one per block)
    ph_out(p, bid >> 4, bid & 15, smem);
    grid.sync();

    // P6: chunk-reduce + bias -> out (256 units)
    if (bid < 256) ph_fin(p, bid & 3, bid >> 2, tid);
}

// ---------------- fallback path (separate launches) -------------------------
__global__ __launch_bounds__(256) void f_bnconv(KParams p)
{
    ph_conv(p, blockIdx.x, blockIdx.y, threadIdx.x);
}
__global__ __launch_bounds__(256) void f_lin(KParams p)
{
    __shared__ float smem[12864];
    ph_lin(p, blockIdx.z, blockIdx.y, blockIdx.x, smem);
}
__global__ __launch_bounds__(256) void f_act(KParams p)
{
    ph_act(p, blockIdx.x, blockIdx.y, threadIdx.x);
}
__global__ __launch_bounds__(256) void f_attn(KParams p)
{
    __shared__ float smem[2568];
    ph_attn(p, blockIdx.x, blockIdx.y, threadIdx.x, smem);
}
__global__ __launch_bounds__(256) void f_out(KParams p)
{
    __shared__ float smem[12864];
    ph_out(p, blockIdx.y, blockIdx.x, smem);
}
__global__ __launch_bounds__(256) void f_fin(KParams p)
{
    ph_fin(p, blockIdx.x, blockIdx.y, threadIdx.x);
}

extern "C" void kernel_launch(void* const* d_in, const int* in_sizes, int n_in,
                              void* d_out, int out_size, void* d_ws, size_t ws_size,
                              hipStream_t stream)
{
    float* ws = (float*)d_ws;
    KParams p;
    p.x    = (const float*)d_in[0];
    p.g    = (const float*)d_in[1];
    p.be   = (const float*)d_in[2];
    p.mu   = (const float*)d_in[3];
    p.va   = (const float*)d_in[4];
    p.cwq  = (const float*)d_in[5];
    p.cbq  = (const float*)d_in[6];
    p.lwq  = (const float*)d_in[7];
    p.lbq  = (const float*)d_in[8];
    p.cwk  = (const float*)d_in[9];
    p.cbk  = (const float*)d_in[10];
    p.lwk  = (const float*)d_in[11];
    p.lbk  = (const float*)d_in[12];
    p.cwv  = (const float*)d_in[13];
    p.cbv  = (const float*)d_in[14];
    p.lwv  = (const float*)d_in[15];
    p.lbv  = (const float*)d_in[16];
    p.ipw  = (const float*)d_in[17];
    p.ipb  = (const float*)d_in[18];
    p.opw  = (const float*)d_in[19];
    p.opb  = (const float*)d_in[20];
    p.W    = (const float*)d_in[21];
    p.outb = (const float*)d_in[22];
    p.convT = ws + OFF_CONVT;
    p.Pp    = ws + OFF_PP;
    p.q     = ws + OFF_Q;
    p.kv    = ws + OFF_KV;
    p.cfT   = ws + OFF_CF;
    p.Op    = ws + OFF_OP;
    p.out   = (float*)d_out;

    void* args[] = { &p };
    hipError_t e = hipLaunchCooperativeKernel((const void*)k_all,
                                              dim3(GRID_BLOCKS), dim3(256),
                                              args, 0, stream);
    if (e != hipSuccess) {
        // fallback: proven 6-kernel pipeline with the rebalanced chunking
        f_bnconv<<<dim3(4, 64), 256, 0, stream>>>(p);
        f_lin  <<<dim3(16, 3, NCHL), 256, 0, stream>>>(p);
        f_act  <<<dim3(4, 64), 256, 0, stream>>>(p);
        f_attn <<<dim3(16, 64), 256, 0, stream>>>(p);
        f_out  <<<dim3(16, NCHO), 256, 0, stream>>>(p);
        f_fin  <<<dim3(4, 64), 256, 0, stream>>>(p);
    }
}

// Round 3
// 178.132 us; speedup vs baseline: 2.6802x; 2.6802x over previous
//
#include <hip/hip_runtime.h>
#include <math.h>

#define NB 64
#define LIN 4001
#define LC 998
#define ND 1000
#define EPSBN 1e-5f

#define CKL 100          // K-chunk for QKV GEMM -> 10 chunks
#define NCHL 10
#define CKO 96           // K-chunk for out GEMM -> 11 chunks
#define NCHO 11

// ws float offsets
#define OFF_CONVT 0u          // 3*998*64     = 191616
#define OFF_PP    191616u     // 10*3*16*4096 = 1966080
#define OFF_CF    2157696u    // 1000*64      = 64000
#define OFF_OP    2221696u    // 11*16*4096   = 720896
// end = 2942592 floats = 11.8 MB

// ---------------- K1: fused BatchNorm + strided conv -> convT[w][j][b] ------
__global__ __launch_bounds__(256) void k_bnconv(
    const float* __restrict__ x,
    const float* __restrict__ g, const float* __restrict__ be,
    const float* __restrict__ mu, const float* __restrict__ va,
    const float* __restrict__ cwq, const float* __restrict__ cbq,
    const float* __restrict__ cwk, const float* __restrict__ cbk,
    const float* __restrict__ cwv, const float* __restrict__ cbv,
    float* __restrict__ convT)
{
    int j = blockIdx.x * 256 + threadIdx.x;
    int b = blockIdx.y;
    if (j >= LC) return;
    const float* xb = x + (size_t)b * LIN + 4 * j;
    float aq = 0.f, ak = 0.f, av = 0.f;
#pragma unroll
    for (int t = 0; t < 10; ++t) {
        int i = 4 * j + t;
        float s  = g[i] * rsqrtf(va[i] + EPSBN);
        float xn = (xb[t] - mu[i]) * s + be[i];
        aq = fmaf(xn, cwq[t], aq);
        ak = fmaf(xn, cwk[t], ak);
        av = fmaf(xn, cwv[t], av);
    }
    convT[((size_t)0 * LC + j) * 64 + b] = aq + cbq[0];
    convT[((size_t)1 * LC + j) * 64 + b] = ak + cbk[0];
    convT[((size_t)2 * LC + j) * 64 + b] = av + cbv[0];
}

// ---------------- shared GEMM microtile body (64b x 64d x CKT) --------------
template <int CKT>
__device__ __forceinline__ void gemm_tile(
    const float* __restrict__ Asrc,   // [jc][64] chunk, b-contiguous
    const float* __restrict__ Brow,   // weight base, row stride ldB
    int ldB, int dgb, int j0, int jc,
    float* __restrict__ Pt,           // output tile [64 b][64 d]
    float* lds)
{
    constexpr int LDW = CKT + 1;
    constexpr int F2R = CKT / 2;
    float* ldsC = lds;                // [CKT][64]
    float* ldsW = lds + CKT * 64;     // [64][LDW]
    int tid  = threadIdx.x;
    int lane = tid & 63;
    int w    = tid >> 6;
    int b0   = (lane & 7) << 3;
    int d0   = (lane >> 3) << 3;

    {   // stage A chunk via float4 (fully coalesced)
        const float4* src = (const float4*)Asrc;
        float4* dst = (float4*)ldsC;
        int n = jc * 16;
        for (int t = tid; t < n; t += 256) dst[t] = src[t];
    }
    // stage B tile via float2 (row starts & j0 are even)
    for (int idx = tid; idx < 64 * F2R; idx += 256) {
        int dd = idx / F2R, j2 = idx % F2R;
        int dg = dgb + dd;
        float2 v = make_float2(0.f, 0.f);
        if (dg < ND && 2 * j2 < jc)
            v = *(const float2*)(Brow + (size_t)dg * ldB + j0 + 2 * j2);
        ldsW[dd * LDW + 2 * j2]     = v.x;
        ldsW[dd * LDW + 2 * j2 + 1] = v.y;
    }
    __syncthreads();

    float acc[8][8];
#pragma unroll
    for (int i = 0; i < 8; ++i)
#pragma unroll
        for (int jx = 0; jx < 8; ++jx) acc[i][jx] = 0.f;

    int js = (jc * w) >> 2;
    int je = (jc * (w + 1)) >> 2;
#pragma unroll 2
    for (int jj = js; jj < je; ++jj) {
        float4 c0 = *(const float4*)(ldsC + jj * 64 + b0);
        float4 c1 = *(const float4*)(ldsC + jj * 64 + b0 + 4);
        float cv[8] = {c0.x, c0.y, c0.z, c0.w, c1.x, c1.y, c1.z, c1.w};
        float wv[8];
#pragma unroll
        for (int r = 0; r < 8; ++r) wv[r] = ldsW[(d0 + r) * LDW + jj];
#pragma unroll
        for (int i = 0; i < 8; ++i)
#pragma unroll
            for (int jx = 0; jx < 8; ++jx)
                acc[i][jx] = fmaf(cv[i], wv[jx], acc[i][jx]);
    }
    __syncthreads();   // done with staged data; reuse LDS for reduce

    // two passes (f4 halves of each lane's d-range); per-wave buf [64][36]
    for (int p = 0; p < 2; ++p) {
        float* red = lds + w * 2304;
#pragma unroll
        for (int i = 0; i < 8; ++i)
            *(float4*)(red + (b0 + i) * 36 + (d0 >> 1)) =
                make_float4(acc[i][4*p], acc[i][4*p+1], acc[i][4*p+2], acc[i][4*p+3]);
        __syncthreads();
        for (int t = tid; t < 512; t += 256) {
            int bb = t >> 3, gg = t & 7;
            int o = bb * 36 + 4 * gg;
            float4 a0 = *(const float4*)(lds + o);
            float4 a1 = *(const float4*)(lds + 2304 + o);
            float4 a2 = *(const float4*)(lds + 4608 + o);
            float4 a3 = *(const float4*)(lds + 6912 + o);
            float4 s;
            s.x = a0.x + a1.x + a2.x + a3.x;
            s.y = a0.y + a1.y + a2.y + a3.y;
            s.z = a0.z + a1.z + a2.z + a3.z;
            s.w = a0.w + a1.w + a2.w + a3.w;
            *(float4*)(Pt + bb * 64 + 8 * gg + 4 * p) = s;
        }
        __syncthreads();
    }
}

// ---------------- K2: QKV GEMM partials -> Pp (no atomics) ------------------
__global__ __launch_bounds__(256) void k_lin(
    const float* __restrict__ convT,
    const float* __restrict__ lwq, const float* __restrict__ lwk,
    const float* __restrict__ lwv,
    float* __restrict__ Pp)
{
    __shared__ float lds[12864];
    int dgb   = blockIdx.x * 64;
    int which = blockIdx.y;
    int chunk = blockIdx.z;
    int j0 = chunk * CKL;
    int jc = (LC - j0 < CKL) ? (LC - j0) : CKL;
    const float* lw = (which == 0) ? lwq : ((which == 1) ? lwk : lwv);
    const float* Asrc = convT + ((size_t)which * LC + j0) * 64;
    float* Pt = Pp + (((size_t)chunk * 3 + which) * 16 + blockIdx.x) * 4096;
    gemm_tile<CKL>(Asrc, lw, LC, dgb, j0, jc, Pt, lds);
}

// ---------------- K3: fused chunk-reduce + bias + ReLU + in_proj + attention
// grid (4 i-quarters, 64 b); each block reduces k/v partials for ALL i of its
// batch into LDS, its own q-range into registers, then full-length softmax.
__global__ __launch_bounds__(256) void k_actattn(
    const float* __restrict__ Pp,
    const float* __restrict__ lbq, const float* __restrict__ lbk,
    const float* __restrict__ lbv,
    const float* __restrict__ ipw, const float* __restrict__ ipb,
    const float* __restrict__ opw, const float* __restrict__ opb,
    float* __restrict__ cfT)
{
    __shared__ float ldsKV[2048];
    __shared__ float rmax[4];
    __shared__ float rmin[4];
    int tid = threadIdx.x;
    int iq  = blockIdx.x;
    int b   = blockIdx.y;
    int w   = tid >> 6;

    // act: reduce partial sums for k,v over all i (coalesced within 64-seg)
    for (int i = tid; i < ND; i += 256) {
        int ig  = i >> 6;
        int off = (i & 63) | (b << 6);
        float s1 = 0.f, s2 = 0.f;
#pragma unroll
        for (int c = 0; c < NCHL; ++c) {
            size_t base = (((size_t)c * 3 + 1) * 16 + ig) * 4096 + off;
            s1 += Pp[base];
            s2 += Pp[base + 16 * 4096];
        }
        ldsKV[2 * i]     = fmaxf(s1 + lbk[i], 0.f) * ipw[1] + ipb[1];
        ldsKV[2 * i + 1] = fmaxf(s2 + lbv[i], 0.f) * ipw[2] + ipb[2];
    }
    // act: own q-range (250 rows per block)
    int  i   = iq * 250 + tid;
    bool act = (tid < 250);
    float qi = 0.f;
    if (act) {
        int ig  = i >> 6;
        int off = (i & 63) | (b << 6);
        float s0 = 0.f;
#pragma unroll
        for (int c = 0; c < NCHL; ++c)
            s0 += Pp[(((size_t)c * 3) * 16 + ig) * 4096 + off];
        qi = fmaxf(s0 + lbq[i], 0.f) * ipw[0] + ipb[0];
    }
    __syncthreads();

    // k max/min for the stable-softmax shift
    const float2* kv2 = (const float2*)ldsKV;
    float km = -INFINITY, kn = INFINITY;
    for (int idx = tid; idx < ND; idx += 256) {
        float2 f = kv2[idx];
        km = fmaxf(km, f.x);
        kn = fminf(kn, f.x);
    }
#pragma unroll
    for (int off = 1; off < 64; off <<= 1) {
        km = fmaxf(km, __shfl_xor(km, off));
        kn = fminf(kn, __shfl_xor(kn, off));
    }
    if ((tid & 63) == 0) { rmax[w] = km; rmin[w] = kn; }
    __syncthreads();
    km = fmaxf(fmaxf(rmax[0], rmax[1]), fmaxf(rmax[2], rmax[3]));
    kn = fminf(fminf(rmin[0], rmin[1]), fminf(rmin[2], rmin[3]));

    float m = (qi >= 0.f) ? qi * km : qi * kn;
    float den = 0.f, num = 0.f;
#pragma unroll 4
    for (int j = 0; j < ND; ++j) {
        float2 f = kv2[j];                       // broadcast read, conflict-free
        float e  = __expf(fmaf(qi, f.x, -m));
        den += e;
        num = fmaf(e, f.y, num);
    }
    if (act)
        cfT[(size_t)i * 64 + b] = (num / den) * opw[0] + opb[0];
}

// ---------------- K4: out GEMM partials -> Op (no atomics) ------------------
__global__ __launch_bounds__(256) void k_out(
    const float* __restrict__ cfT, const float* __restrict__ W,
    float* __restrict__ Op)
{
    __shared__ float lds[12352];
    int egb   = blockIdx.x * 64;
    int chunk = blockIdx.y;
    int j0 = chunk * CKO;
    int jc = (ND - j0 < CKO) ? (ND - j0) : CKO;
    const float* Asrc = cfT + (size_t)j0 * 64;
    float* Pt = Op + ((size_t)chunk * 16 + blockIdx.x) * 4096;
    gemm_tile<CKO>(Asrc, W, ND, egb, j0, jc, Pt, lds);
}

// ---------------- K5: reduce Op chunks + bias -> out ------------------------
__global__ __launch_bounds__(256) void k_fin(
    const float* __restrict__ Op, const float* __restrict__ outb,
    float* __restrict__ out)
{
    int e = blockIdx.x * 256 + threadIdx.x;
    int b = blockIdx.y;
    if (e >= ND) return;
    float s = outb[e];
    size_t cell = ((size_t)(e >> 6)) * 4096 + (b << 6) + (e & 63);
    for (int c = 0; c < NCHO; ++c)
        s += Op[(size_t)c * 16 * 4096 + cell];
    out[(size_t)b * ND + e] = s;
}

extern "C" void kernel_launch(void* const* d_in, const int* in_sizes, int n_in,
                              void* d_out, int out_size, void* d_ws, size_t ws_size,
                              hipStream_t stream)
{
    const float* x    = (const float*)d_in[0];
    const float* g    = (const float*)d_in[1];
    const float* be   = (const float*)d_in[2];
    const float* mu   = (const float*)d_in[3];
    const float* va   = (const float*)d_in[4];
    const float* cwq  = (const float*)d_in[5];
    const float* cbq  = (const float*)d_in[6];
    const float* lwq  = (const float*)d_in[7];
    const float* lbq  = (const float*)d_in[8];
    const float* cwk  = (const float*)d_in[9];
    const float* cbk  = (const float*)d_in[10];
    const float* lwk  = (const float*)d_in[11];
    const float* lbk  = (const float*)d_in[12];
    const float* cwv  = (const float*)d_in[13];
    const float* cbv  = (const float*)d_in[14];
    const float* lwv  = (const float*)d_in[15];
    const float* lbv  = (const float*)d_in[16];
    const float* ipw  = (const float*)d_in[17];
    const float* ipb  = (const float*)d_in[18];
    const float* opw  = (const float*)d_in[19];
    const float* opb  = (const float*)d_in[20];
    const float* W    = (const float*)d_in[21];
    const float* outb = (const float*)d_in[22];

    float* ws    = (float*)d_ws;
    float* convT = ws + OFF_CONVT;
    float* Pp    = ws + OFF_PP;
    float* cfT   = ws + OFF_CF;
    float* Op    = ws + OFF_OP;
    float* out   = (float*)d_out;

    k_bnconv <<<dim3(4, 64), 256, 0, stream>>>(x, g, be, mu, va,
                                               cwq, cbq, cwk, cbk, cwv, cbv, convT);
    k_lin    <<<dim3(16, 3, NCHL), 256, 0, stream>>>(convT, lwq, lwk, lwv, Pp);
    k_actattn<<<dim3(4, 64), 256, 0, stream>>>(Pp, lbq, lbk, lbv,
                                               ipw, ipb, opw, opb, cfT);
    k_out    <<<dim3(16, NCHO), 256, 0, stream>>>(cfT, W, Op);
    k_fin    <<<dim3(4, 64), 256, 0, stream>>>(Op, outb, out);
}